// Round 1
// baseline (6082.269 us; speedup 1.0000x reference)
//
#include <hip/hip_runtime.h>

// GraphSAGE (pool aggregator, 2 layers) on MI355X.
// Round 1: correct fp32 implementation.
//   - weights pre-transposed to Wt[k][n] (coalesced LDS staging, conflict-free)
//   - segment_max via integer atomicMax on non-negative (post-ReLU) floats,
//     zero-init == where(isfinite, agg, 0) semantics
//   - read-before-atomic filter to cut atomic traffic (~5x expected)

#define N_FEAT 128

__global__ void prep_kernel(const float* __restrict__ pw1, const float* __restrict__ sw1,
                            const float* __restrict__ nw1, const float* __restrict__ pw2,
                            const float* __restrict__ sw2, const float* __restrict__ nw2,
                            const float* __restrict__ sb1, const float* __restrict__ nb1,
                            const float* __restrict__ sb2, const float* __restrict__ nb2,
                            float* __restrict__ wt_p1, float* __restrict__ wt_s1,
                            float* __restrict__ wt_n1, float* __restrict__ wt_p2,
                            float* __restrict__ wt_s2, float* __restrict__ wt_n2,
                            float* __restrict__ b_sn1, float* __restrict__ b_sn2)
{
    int t = blockIdx.x * 256 + threadIdx.x;
    if (t < 16384) {                      // 128x128 transposes: Wt[k*128+n] = W[n*128+k]
        int k = t >> 7, n = t & 127;
        wt_p1[t] = pw1[n * 128 + k];
        wt_s1[t] = sw1[n * 128 + k];
        wt_n1[t] = nw1[n * 128 + k];
        wt_p2[t] = pw2[n * 128 + k];
    }
    if (t < 5120) {                       // 40x128 transposes: Wt[k*40+n] = W[n*128+k]
        int k = t / 40, n = t % 40;
        wt_s2[t] = sw2[n * 128 + k];
        wt_n2[t] = nw2[n * 128 + k];
    }
    if (t < 128) b_sn1[t] = sb1[t] + nb1[t];
    if (t < 40)  b_sn2[t] = sb2[t] + nb2[t];
}

__global__ void zero_kernel(float4* __restrict__ p, int n4)
{
    int i = blockIdx.x * 256 + threadIdx.x;
    if (i < n4) p[i] = make_float4(0.f, 0.f, 0.f, 0.f);
}

// C[M,N] = act( sum_p A_p[M,128] @ Wt_p[128,N] + bias[N] )
// 256 threads; CGS=N/CPT col-groups, RGS=256/CGS row-groups, MT=RGS*RPT rows/block.
template<int N, int CPT, int RPT, bool RELU, int NPAIRS>
__global__ __launch_bounds__(256) void gemm_kernel(
    const float* __restrict__ A0, const float* __restrict__ Wt0,
    const float* __restrict__ A1, const float* __restrict__ Wt1,
    const float* __restrict__ bias, float* __restrict__ C, int M)
{
    constexpr int CGS = N / CPT;
    constexpr int RGS = 256 / CGS;
    constexpr int MT = RGS * RPT;
    __shared__ float Ws[128 * N];
    __shared__ float Bs[N];
    const int tid = threadIdx.x;
    const int rg = tid / CGS;
    const int cg = tid % CGS;
    const int m0 = blockIdx.x * MT;
    const int c0 = cg * CPT;

    float acc[RPT][CPT];
#pragma unroll
    for (int i = 0; i < RPT; i++)
#pragma unroll
        for (int j = 0; j < CPT; j++) acc[i][j] = 0.f;

    if (tid < N) Bs[tid] = bias[tid];

    int row[RPT];
#pragma unroll
    for (int i = 0; i < RPT; i++) row[i] = m0 + rg + i * RGS;

#pragma unroll
    for (int p = 0; p < NPAIRS; p++) {
        const float* __restrict__ A  = (p == 0) ? A0 : A1;
        const float* __restrict__ Wt = (p == 0) ? Wt0 : Wt1;
        if (p) __syncthreads();                      // done reading previous Ws
        for (int i = tid; i < 128 * N; i += 256) Ws[i] = Wt[i];
        __syncthreads();

        const float4* __restrict__ A4 = (const float4*)A;
        for (int k0 = 0; k0 < 128; k0 += 4) {
            float a[RPT][4];
#pragma unroll
            for (int i = 0; i < RPT; i++) {
                float4 t = make_float4(0.f, 0.f, 0.f, 0.f);
                if (row[i] < M) t = A4[row[i] * 32 + (k0 >> 2)];
                a[i][0] = t.x; a[i][1] = t.y; a[i][2] = t.z; a[i][3] = t.w;
            }
#pragma unroll
            for (int kk = 0; kk < 4; kk++) {
                const float* __restrict__ wrow = &Ws[(k0 + kk) * N + c0];
#pragma unroll
                for (int j = 0; j < CPT; j++) {
                    float w = wrow[j];
#pragma unroll
                    for (int i = 0; i < RPT; i++) acc[i][j] += a[i][kk] * w;
                }
            }
        }
    }

#pragma unroll
    for (int i = 0; i < RPT; i++) {
        if (row[i] < M) {
#pragma unroll
            for (int j = 0; j < CPT; j++) {
                float v = acc[i][j] + Bs[c0 + j];
                if (RELU) v = fmaxf(v, 0.f);
                C[row[i] * N + c0 + j] = v;
            }
        }
    }
}

// agg[dst] = max over edges of m[src]; m >= 0 (post-ReLU) so int compare == float
// compare; agg zero-initialized (also covers isolated nodes -> 0 per reference).
__global__ void scatter_max_kernel(const float* __restrict__ m, const int* __restrict__ src,
                                   const int* __restrict__ dst, int* __restrict__ agg, int E)
{
    int gid = blockIdx.x * 256 + threadIdx.x;
    int e = gid >> 5;          // 32 lanes per edge, float4 per lane
    int lane = gid & 31;
    if (e >= E) return;
    int s = src[e], d = dst[e];
    int4 v = ((const int4*)m)[s * 32 + lane];            // non-neg float bits
    int4 cur = ((const int4*)agg)[d * 32 + lane];
    int base = d * 128 + lane * 4;
    if (v.x > cur.x) atomicMax(&agg[base + 0], v.x);
    if (v.y > cur.y) atomicMax(&agg[base + 1], v.y);
    if (v.z > cur.z) atomicMax(&agg[base + 2], v.z);
    if (v.w > cur.w) atomicMax(&agg[base + 3], v.w);
}

extern "C" void kernel_launch(void* const* d_in, const int* in_sizes, int n_in,
                              void* d_out, int out_size, void* d_ws, size_t ws_size,
                              hipStream_t stream)
{
    const float* in_feat = (const float*)d_in[0];
    const int*   src     = (const int*)d_in[1];
    const int*   dst     = (const int*)d_in[2];
    const float* pw1 = (const float*)d_in[3];  const float* pb1 = (const float*)d_in[4];
    const float* sw1 = (const float*)d_in[5];  const float* sb1 = (const float*)d_in[6];
    const float* nw1 = (const float*)d_in[7];  const float* nb1 = (const float*)d_in[8];
    const float* pw2 = (const float*)d_in[9];  const float* pb2 = (const float*)d_in[10];
    const float* sw2 = (const float*)d_in[11]; const float* sb2 = (const float*)d_in[12];
    const float* nw2 = (const float*)d_in[13]; const float* nb2 = (const float*)d_in[14];
    float* out = (float*)d_out;

    const int M = in_sizes[0] / N_FEAT;   // 100000
    const int E = in_sizes[1];            // 1600000

    float* ws    = (float*)d_ws;
    float* wt_p1 = ws;                    // 16384
    float* wt_s1 = wt_p1 + 16384;
    float* wt_n1 = wt_s1 + 16384;
    float* wt_p2 = wt_n1 + 16384;
    float* wt_s2 = wt_p2 + 16384;         // 5120
    float* wt_n2 = wt_s2 + 5120;
    float* b_sn1 = wt_n2 + 5120;          // 128
    float* b_sn2 = b_sn1 + 128;           // 40 (pad to 64)
    float* mbuf  = b_sn2 + 64;            // M*128
    float* aggbuf = mbuf + (size_t)M * N_FEAT;
    float* h1buf  = aggbuf + (size_t)M * N_FEAT;

    const int gemm_grid = (M + 63) / 64;
    const int n4 = (M * N_FEAT) / 4;
    const int zero_grid = (n4 + 255) / 256;
    const int scat_grid = (E * 32 + 255) / 256;

    prep_kernel<<<64, 256, 0, stream>>>(pw1, sw1, nw1, pw2, sw2, nw2,
                                        sb1, nb1, sb2, nb2,
                                        wt_p1, wt_s1, wt_n1, wt_p2, wt_s2, wt_n2,
                                        b_sn1, b_sn2);

    // Layer 1
    gemm_kernel<128, 8, 4, true, 1><<<gemm_grid, 256, 0, stream>>>(
        in_feat, wt_p1, nullptr, nullptr, pb1, mbuf, M);
    zero_kernel<<<zero_grid, 256, 0, stream>>>((float4*)aggbuf, n4);
    scatter_max_kernel<<<scat_grid, 256, 0, stream>>>(mbuf, src, dst, (int*)aggbuf, E);
    gemm_kernel<128, 8, 4, true, 2><<<gemm_grid, 256, 0, stream>>>(
        in_feat, wt_s1, aggbuf, wt_n1, b_sn1, h1buf, M);

    // Layer 2
    gemm_kernel<128, 8, 4, true, 1><<<gemm_grid, 256, 0, stream>>>(
        h1buf, wt_p2, nullptr, nullptr, pb2, mbuf, M);
    zero_kernel<<<zero_grid, 256, 0, stream>>>((float4*)aggbuf, n4);
    scatter_max_kernel<<<scat_grid, 256, 0, stream>>>(mbuf, src, dst, (int*)aggbuf, E);
    gemm_kernel<40, 5, 2, false, 2><<<gemm_grid, 256, 0, stream>>>(
        h1buf, wt_s2, aggbuf, wt_n2, b_sn2, out, M);
}

// Round 2
// 2279.228 us; speedup vs baseline: 2.6686x; 2.6686x over previous
//
#include <hip/hip_runtime.h>

// GraphSAGE (pool aggregator, 2 layers) on MI355X.
// Round 2: fix the round-1 pathology — the N=40 GEMM spilled to scratch
// (WRITE_SIZE 2.25 GB vs 16 MB of C; VGPR=256; VALUBusy 1%).
//   - __launch_bounds__(256,4): cap VGPRs at 128 -> no spill, 16 waves/CU
//   - K-tiled weight staging (KT=32): LDS 16.5 KB (N=128) / 5.2 KB (N=40)
//     instead of 66 KB -> higher occupancy
//   - no unroll on the pair loop; clamp rows for loads, guard only stores

#define N_FEAT 128

__global__ void prep_kernel(const float* __restrict__ pw1, const float* __restrict__ sw1,
                            const float* __restrict__ nw1, const float* __restrict__ pw2,
                            const float* __restrict__ sw2, const float* __restrict__ nw2,
                            const float* __restrict__ sb1, const float* __restrict__ nb1,
                            const float* __restrict__ sb2, const float* __restrict__ nb2,
                            float* __restrict__ wt_p1, float* __restrict__ wt_s1,
                            float* __restrict__ wt_n1, float* __restrict__ wt_p2,
                            float* __restrict__ wt_s2, float* __restrict__ wt_n2,
                            float* __restrict__ b_sn1, float* __restrict__ b_sn2)
{
    int t = blockIdx.x * 256 + threadIdx.x;
    if (t < 16384) {                      // 128x128 transposes: Wt[k*128+n] = W[n*128+k]
        int k = t >> 7, n = t & 127;
        wt_p1[t] = pw1[n * 128 + k];
        wt_s1[t] = sw1[n * 128 + k];
        wt_n1[t] = nw1[n * 128 + k];
        wt_p2[t] = pw2[n * 128 + k];
    }
    if (t < 5120) {                       // 40x128 transposes: Wt[k*40+n] = W[n*128+k]
        int k = t / 40, n = t % 40;
        wt_s2[t] = sw2[n * 128 + k];
        wt_n2[t] = nw2[n * 128 + k];
    }
    if (t < 128) b_sn1[t] = sb1[t] + nb1[t];
    if (t < 40)  b_sn2[t] = sb2[t] + nb2[t];
}

__global__ void zero_kernel(float4* __restrict__ p, int n4)
{
    int i = blockIdx.x * 256 + threadIdx.x;
    if (i < n4) p[i] = make_float4(0.f, 0.f, 0.f, 0.f);
}

// C[M,N] = act( sum_p A_p[M,128] @ Wt_p[128,N] + bias[N] )
// 256 threads; CGS=N/CPT col-groups, RGS=256/CGS row-groups, MT=RGS*RPT rows/block.
// K-tiled: stage KT rows of Wt at a time in LDS.
template<int N, int CPT, int RPT, bool RELU, int NPAIRS>
__global__ __launch_bounds__(256, 4) void gemm_kernel(
    const float* __restrict__ A0, const float* __restrict__ Wt0,
    const float* __restrict__ A1, const float* __restrict__ Wt1,
    const float* __restrict__ bias, float* __restrict__ C, int M)
{
    constexpr int CGS = N / CPT;
    constexpr int RGS = 256 / CGS;
    constexpr int MT = RGS * RPT;
    constexpr int KT = 32;
    __shared__ float Ws[KT * N];
    __shared__ float Bs[N];
    const int tid = threadIdx.x;
    const int rg = tid / CGS;
    const int cg = tid % CGS;
    const int m0 = blockIdx.x * MT;
    const int c0 = cg * CPT;

    float acc[RPT][CPT];
#pragma unroll
    for (int i = 0; i < RPT; i++)
#pragma unroll
        for (int j = 0; j < CPT; j++) acc[i][j] = 0.f;

    if (tid < N) Bs[tid] = bias[tid];

    int rowr[RPT], rowl[RPT];
#pragma unroll
    for (int i = 0; i < RPT; i++) {
        rowr[i] = m0 + rg + i * RGS;
        rowl[i] = rowr[i] < M ? rowr[i] : (M - 1);   // clamp for loads; guard stores only
    }

    for (int p = 0; p < NPAIRS; p++) {               // NOT unrolled: keep body small
        const float4* __restrict__ A4 = (const float4*)((p == 0) ? A0 : A1);
        const float* __restrict__ Wt = (p == 0) ? Wt0 : Wt1;
        for (int kt = 0; kt < 128; kt += KT) {
            __syncthreads();                         // previous tile fully consumed
            for (int i = tid; i < KT * N; i += 256) Ws[i] = Wt[kt * N + i];
            __syncthreads();

            for (int k04 = 0; k04 < KT / 4; k04++) {
                float a[RPT][4];
#pragma unroll
                for (int i = 0; i < RPT; i++) {
                    float4 t = A4[rowl[i] * 32 + (kt >> 2) + k04];
                    a[i][0] = t.x; a[i][1] = t.y; a[i][2] = t.z; a[i][3] = t.w;
                }
#pragma unroll
                for (int kk = 0; kk < 4; kk++) {
                    const float* __restrict__ wrow = &Ws[(k04 * 4 + kk) * N + c0];
#pragma unroll
                    for (int j = 0; j < CPT; j++) {
                        float w = wrow[j];
#pragma unroll
                        for (int i = 0; i < RPT; i++) acc[i][j] += a[i][kk] * w;
                    }
                }
            }
        }
    }

#pragma unroll
    for (int i = 0; i < RPT; i++) {
        if (rowr[i] < M) {
#pragma unroll
            for (int j = 0; j < CPT; j++) {
                float v = acc[i][j] + Bs[c0 + j];
                if (RELU) v = fmaxf(v, 0.f);
                C[rowr[i] * N + c0 + j] = v;
            }
        }
    }
}

// agg[dst] = max over edges of m[src]; m >= 0 (post-ReLU) so int compare == float
// compare; agg zero-initialized (also covers isolated nodes -> 0 per reference).
__global__ void scatter_max_kernel(const float* __restrict__ m, const int* __restrict__ src,
                                   const int* __restrict__ dst, int* __restrict__ agg, int E)
{
    int gid = blockIdx.x * 256 + threadIdx.x;
    int e = gid >> 5;          // 32 lanes per edge, float4 per lane
    int lane = gid & 31;
    if (e >= E) return;
    int s = src[e], d = dst[e];
    int4 v = ((const int4*)m)[s * 32 + lane];            // non-neg float bits
    int4 cur = ((const int4*)agg)[d * 32 + lane];
    int base = d * 128 + lane * 4;
    if (v.x > cur.x) atomicMax(&agg[base + 0], v.x);
    if (v.y > cur.y) atomicMax(&agg[base + 1], v.y);
    if (v.z > cur.z) atomicMax(&agg[base + 2], v.z);
    if (v.w > cur.w) atomicMax(&agg[base + 3], v.w);
}

extern "C" void kernel_launch(void* const* d_in, const int* in_sizes, int n_in,
                              void* d_out, int out_size, void* d_ws, size_t ws_size,
                              hipStream_t stream)
{
    const float* in_feat = (const float*)d_in[0];
    const int*   src     = (const int*)d_in[1];
    const int*   dst     = (const int*)d_in[2];
    const float* pw1 = (const float*)d_in[3];  const float* pb1 = (const float*)d_in[4];
    const float* sw1 = (const float*)d_in[5];  const float* sb1 = (const float*)d_in[6];
    const float* nw1 = (const float*)d_in[7];  const float* nb1 = (const float*)d_in[8];
    const float* pw2 = (const float*)d_in[9];  const float* pb2 = (const float*)d_in[10];
    const float* sw2 = (const float*)d_in[11]; const float* sb2 = (const float*)d_in[12];
    const float* nw2 = (const float*)d_in[13]; const float* nb2 = (const float*)d_in[14];
    float* out = (float*)d_out;

    const int M = in_sizes[0] / N_FEAT;   // 100000
    const int E = in_sizes[1];            // 1600000

    float* ws    = (float*)d_ws;
    float* wt_p1 = ws;                    // 16384
    float* wt_s1 = wt_p1 + 16384;
    float* wt_n1 = wt_s1 + 16384;
    float* wt_p2 = wt_n1 + 16384;
    float* wt_s2 = wt_p2 + 16384;         // 5120
    float* wt_n2 = wt_s2 + 5120;
    float* b_sn1 = wt_n2 + 5120;          // 128
    float* b_sn2 = b_sn1 + 128;           // 40 (pad to 64)
    float* mbuf  = b_sn2 + 64;            // M*128
    float* aggbuf = mbuf + (size_t)M * N_FEAT;
    float* h1buf  = aggbuf + (size_t)M * N_FEAT;

    const int gemm_grid = (M + 63) / 64;
    const int n4 = (M * N_FEAT) / 4;
    const int zero_grid = (n4 + 255) / 256;
    const int scat_grid = (E * 32 + 255) / 256;

    prep_kernel<<<64, 256, 0, stream>>>(pw1, sw1, nw1, pw2, sw2, nw2,
                                        sb1, nb1, sb2, nb2,
                                        wt_p1, wt_s1, wt_n1, wt_p2, wt_s2, wt_n2,
                                        b_sn1, b_sn2);

    // Layer 1
    gemm_kernel<128, 8, 4, true, 1><<<gemm_grid, 256, 0, stream>>>(
        in_feat, wt_p1, nullptr, nullptr, pb1, mbuf, M);
    zero_kernel<<<zero_grid, 256, 0, stream>>>((float4*)aggbuf, n4);
    scatter_max_kernel<<<scat_grid, 256, 0, stream>>>(mbuf, src, dst, (int*)aggbuf, E);
    gemm_kernel<128, 8, 4, true, 2><<<gemm_grid, 256, 0, stream>>>(
        in_feat, wt_s1, aggbuf, wt_n1, b_sn1, h1buf, M);

    // Layer 2
    gemm_kernel<128, 8, 4, true, 1><<<gemm_grid, 256, 0, stream>>>(
        h1buf, wt_p2, nullptr, nullptr, pb2, mbuf, M);
    zero_kernel<<<zero_grid, 256, 0, stream>>>((float4*)aggbuf, n4);
    scatter_max_kernel<<<scat_grid, 256, 0, stream>>>(mbuf, src, dst, (int*)aggbuf, E);
    gemm_kernel<40, 5, 2, false, 2><<<gemm_grid, 256, 0, stream>>>(
        h1buf, wt_s2, aggbuf, wt_n2, b_sn2, out, M);
}

// Round 3
// 799.138 us; speedup vs baseline: 7.6110x; 2.8521x over previous
//
#include <hip/hip_runtime.h>

// GraphSAGE (pool aggregator, 2 layers) on MI355X.
// Round 3: replace atomic scatter-max (2x993us, atomic-RMW serialization,
// VALUBusy 3%, BW 22%) with on-device CSR build (once; dst shared by both
// layers) + pull-based gather-max (one wave per node, no atomics, each agg
// row written exactly once, zero wasted bytes).

#define N_FEAT 128

__global__ void prep_kernel(const float* __restrict__ pw1, const float* __restrict__ sw1,
                            const float* __restrict__ nw1, const float* __restrict__ pw2,
                            const float* __restrict__ sw2, const float* __restrict__ nw2,
                            const float* __restrict__ sb1, const float* __restrict__ nb1,
                            const float* __restrict__ sb2, const float* __restrict__ nb2,
                            float* __restrict__ wt_p1, float* __restrict__ wt_s1,
                            float* __restrict__ wt_n1, float* __restrict__ wt_p2,
                            float* __restrict__ wt_s2, float* __restrict__ wt_n2,
                            float* __restrict__ b_sn1, float* __restrict__ b_sn2)
{
    int t = blockIdx.x * 256 + threadIdx.x;
    if (t < 16384) {                      // 128x128 transposes: Wt[k*128+n] = W[n*128+k]
        int k = t >> 7, n = t & 127;
        wt_p1[t] = pw1[n * 128 + k];
        wt_s1[t] = sw1[n * 128 + k];
        wt_n1[t] = nw1[n * 128 + k];
        wt_p2[t] = pw2[n * 128 + k];
    }
    if (t < 5120) {                       // 40x128 transposes: Wt[k*40+n] = W[n*128+k]
        int k = t / 40, n = t % 40;
        wt_s2[t] = sw2[n * 128 + k];
        wt_n2[t] = nw2[n * 128 + k];
    }
    if (t < 128) b_sn1[t] = sb1[t] + nb1[t];
    if (t < 40)  b_sn2[t] = sb2[t] + nb2[t];
}

__global__ void zero_int_kernel(int4* __restrict__ p, int n4)
{
    int i = blockIdx.x * 256 + threadIdx.x;
    if (i < n4) p[i] = make_int4(0, 0, 0, 0);
}

// ---------------- CSR build (by dst) ----------------

__global__ void hist_kernel(const int* __restrict__ dst, int* __restrict__ counts, int E)
{
    int e = blockIdx.x * 256 + threadIdx.x;
    if (e < E) atomicAdd(&counts[dst[e]], 1);
}

// Per-block exclusive scan of 1024 elements (256 thr x 4), emit block sums.
__global__ __launch_bounds__(256) void scan1_kernel(const int* __restrict__ counts,
                                                    int* __restrict__ part,
                                                    int* __restrict__ bsums, int Nn)
{
    __shared__ int sh[256];
    int t = threadIdx.x;
    int base = blockIdx.x * 1024 + t * 4;
    int v[4];
#pragma unroll
    for (int k = 0; k < 4; k++) v[k] = (base + k < Nn) ? counts[base + k] : 0;
    int s = v[0] + v[1] + v[2] + v[3];
    sh[t] = s;
    __syncthreads();
    for (int off = 1; off < 256; off <<= 1) {
        int x = (t >= off) ? sh[t - off] : 0;
        __syncthreads();
        sh[t] += x;
        __syncthreads();
    }
    int excl = sh[t] - s;
    int run = excl;
#pragma unroll
    for (int k = 0; k < 4; k++) {
        if (base + k < Nn) part[base + k] = run;
        run += v[k];
    }
    if (t == 255) bsums[blockIdx.x] = sh[255];
}

// Single-block exclusive scan of nb (<=128) block sums, in place.
__global__ __launch_bounds__(128) void scan2_kernel(int* __restrict__ bsums, int nb)
{
    __shared__ int sh[128];
    int t = threadIdx.x;
    int v = (t < nb) ? bsums[t] : 0;
    sh[t] = v;
    __syncthreads();
    for (int off = 1; off < 128; off <<= 1) {
        int x = (t >= off) ? sh[t - off] : 0;
        __syncthreads();
        sh[t] += x;
        __syncthreads();
    }
    if (t < nb) bsums[t] = sh[t] - v;
}

// offsets[i] = part[i] + bsums[i/1024]; cursor[i] = offsets[i]
__global__ void scan3_kernel(const int* __restrict__ part, const int* __restrict__ bsums,
                             int* __restrict__ offsets, int* __restrict__ cursor, int Nn)
{
    int i = blockIdx.x * 256 + threadIdx.x;
    if (i < Nn) {
        int o = part[i] + bsums[i >> 10];
        offsets[i] = o;
        cursor[i] = o;
    }
}

__global__ void scatter_csr_kernel(const int* __restrict__ src, const int* __restrict__ dst,
                                   int* __restrict__ cursor, int* __restrict__ csr, int E)
{
    int e = blockIdx.x * 256 + threadIdx.x;
    if (e < E) {
        int p = atomicAdd(&cursor[dst[e]], 1);
        csr[p] = src[e];
    }
}

// ---------------- pull-based gather-max ----------------
// One wave per node; lane l owns floats [2l, 2l+1]; neighbor ids batch-loaded
// 64 at a time and shfl-broadcast; 4 rows in flight for MLP. m >= 0 post-ReLU
// and acc starts at 0 => matches where(isfinite(segment_max), ., 0).
__global__ __launch_bounds__(256) void gather_max_kernel(
    const float2* __restrict__ m2, const int* __restrict__ csr,
    const int* __restrict__ offsets, const int* __restrict__ counts,
    float2* __restrict__ agg2, int Nn)
{
    int wid = (blockIdx.x * 256 + threadIdx.x) >> 6;
    int lane = threadIdx.x & 63;
    if (wid >= Nn) return;
    int start = offsets[wid];
    int deg = counts[wid];
    float2 acc = make_float2(0.f, 0.f);
    for (int j0 = 0; j0 < deg; j0 += 64) {
        int nb = deg - j0;
        if (nb > 64) nb = 64;
        int idx = start + j0 + (lane < nb ? lane : nb - 1);
        int sl = csr[idx];
        int j = 0;
        for (; j + 4 <= nb; j += 4) {
            int s0 = __shfl(sl, j + 0), s1 = __shfl(sl, j + 1);
            int s2 = __shfl(sl, j + 2), s3 = __shfl(sl, j + 3);
            float2 v0 = m2[(size_t)s0 * 64 + lane];
            float2 v1 = m2[(size_t)s1 * 64 + lane];
            float2 v2 = m2[(size_t)s2 * 64 + lane];
            float2 v3 = m2[(size_t)s3 * 64 + lane];
            acc.x = fmaxf(fmaxf(fmaxf(acc.x, v0.x), fmaxf(v1.x, v2.x)), v3.x);
            acc.y = fmaxf(fmaxf(fmaxf(acc.y, v0.y), fmaxf(v1.y, v2.y)), v3.y);
        }
        for (; j < nb; j++) {
            int s = __shfl(sl, j);
            float2 v = m2[(size_t)s * 64 + lane];
            acc.x = fmaxf(acc.x, v.x);
            acc.y = fmaxf(acc.y, v.y);
        }
    }
    agg2[(size_t)wid * 64 + lane] = acc;
}

// ---------------- GEMM (unchanged from round 2) ----------------
template<int N, int CPT, int RPT, bool RELU, int NPAIRS>
__global__ __launch_bounds__(256, 4) void gemm_kernel(
    const float* __restrict__ A0, const float* __restrict__ Wt0,
    const float* __restrict__ A1, const float* __restrict__ Wt1,
    const float* __restrict__ bias, float* __restrict__ C, int M)
{
    constexpr int CGS = N / CPT;
    constexpr int RGS = 256 / CGS;
    constexpr int MT = RGS * RPT;
    constexpr int KT = 32;
    __shared__ float Ws[KT * N];
    __shared__ float Bs[N];
    const int tid = threadIdx.x;
    const int rg = tid / CGS;
    const int cg = tid % CGS;
    const int m0 = blockIdx.x * MT;
    const int c0 = cg * CPT;

    float acc[RPT][CPT];
#pragma unroll
    for (int i = 0; i < RPT; i++)
#pragma unroll
        for (int j = 0; j < CPT; j++) acc[i][j] = 0.f;

    if (tid < N) Bs[tid] = bias[tid];

    int rowr[RPT], rowl[RPT];
#pragma unroll
    for (int i = 0; i < RPT; i++) {
        rowr[i] = m0 + rg + i * RGS;
        rowl[i] = rowr[i] < M ? rowr[i] : (M - 1);
    }

    for (int p = 0; p < NPAIRS; p++) {
        const float4* __restrict__ A4 = (const float4*)((p == 0) ? A0 : A1);
        const float* __restrict__ Wt = (p == 0) ? Wt0 : Wt1;
        for (int kt = 0; kt < 128; kt += KT) {
            __syncthreads();
            for (int i = tid; i < KT * N; i += 256) Ws[i] = Wt[kt * N + i];
            __syncthreads();

            for (int k04 = 0; k04 < KT / 4; k04++) {
                float a[RPT][4];
#pragma unroll
                for (int i = 0; i < RPT; i++) {
                    float4 t = A4[rowl[i] * 32 + (kt >> 2) + k04];
                    a[i][0] = t.x; a[i][1] = t.y; a[i][2] = t.z; a[i][3] = t.w;
                }
#pragma unroll
                for (int kk = 0; kk < 4; kk++) {
                    const float* __restrict__ wrow = &Ws[(k04 * 4 + kk) * N + c0];
#pragma unroll
                    for (int j = 0; j < CPT; j++) {
                        float w = wrow[j];
#pragma unroll
                        for (int i = 0; i < RPT; i++) acc[i][j] += a[i][kk] * w;
                    }
                }
            }
        }
    }

#pragma unroll
    for (int i = 0; i < RPT; i++) {
        if (rowr[i] < M) {
#pragma unroll
            for (int j = 0; j < CPT; j++) {
                float v = acc[i][j] + Bs[c0 + j];
                if (RELU) v = fmaxf(v, 0.f);
                C[rowr[i] * N + c0 + j] = v;
            }
        }
    }
}

extern "C" void kernel_launch(void* const* d_in, const int* in_sizes, int n_in,
                              void* d_out, int out_size, void* d_ws, size_t ws_size,
                              hipStream_t stream)
{
    const float* in_feat = (const float*)d_in[0];
    const int*   src     = (const int*)d_in[1];
    const int*   dst     = (const int*)d_in[2];
    const float* pw1 = (const float*)d_in[3];  const float* pb1 = (const float*)d_in[4];
    const float* sw1 = (const float*)d_in[5];  const float* sb1 = (const float*)d_in[6];
    const float* nw1 = (const float*)d_in[7];  const float* nb1 = (const float*)d_in[8];
    const float* pw2 = (const float*)d_in[9];  const float* pb2 = (const float*)d_in[10];
    const float* sw2 = (const float*)d_in[11]; const float* sb2 = (const float*)d_in[12];
    const float* nw2 = (const float*)d_in[13]; const float* nb2 = (const float*)d_in[14];
    float* out = (float*)d_out;

    const int M = in_sizes[0] / N_FEAT;   // 100000 nodes
    const int E = in_sizes[1];            // 1600000 edges

    float* ws    = (float*)d_ws;
    float* wt_p1 = ws;                    // 16384 each
    float* wt_s1 = wt_p1 + 16384;
    float* wt_n1 = wt_s1 + 16384;
    float* wt_p2 = wt_n1 + 16384;
    float* wt_s2 = wt_p2 + 16384;         // 5120 each
    float* wt_n2 = wt_s2 + 5120;
    float* b_sn1 = wt_n2 + 5120;          // 128
    float* b_sn2 = b_sn1 + 128;           // 40 (pad 64)
    float* mbuf   = b_sn2 + 64;           // M*128
    float* aggbuf = mbuf + (size_t)M * N_FEAT;
    float* h1buf  = aggbuf + (size_t)M * N_FEAT;
    int* counts  = (int*)(h1buf + (size_t)M * N_FEAT);  // M
    int* part    = counts + M;                          // M (scan partials -> offsets tmp)
    int* offsets = part + M;                            // M
    int* cursor  = offsets + M;                         // M
    int* bsums   = cursor + M;                          // 128
    int* csr     = bsums + 128;                         // E

    const int gemm_grid = (M + 63) / 64;
    const int edge_grid = (E + 255) / 256;
    const int scan_blocks = (M + 1023) / 1024;          // 98

    prep_kernel<<<64, 256, 0, stream>>>(pw1, sw1, nw1, pw2, sw2, nw2,
                                        sb1, nb1, sb2, nb2,
                                        wt_p1, wt_s1, wt_n1, wt_p2, wt_s2, wt_n2,
                                        b_sn1, b_sn2);

    // ---- CSR build (once; dst identical for both layers) ----
    zero_int_kernel<<<(M / 4 + 255) / 256, 256, 0, stream>>>((int4*)counts, M / 4);
    hist_kernel<<<edge_grid, 256, 0, stream>>>(dst, counts, E);
    scan1_kernel<<<scan_blocks, 256, 0, stream>>>(counts, part, bsums, M);
    scan2_kernel<<<1, 128, 0, stream>>>(bsums, scan_blocks);
    scan3_kernel<<<(M + 255) / 256, 256, 0, stream>>>(part, bsums, offsets, cursor, M);
    scatter_csr_kernel<<<edge_grid, 256, 0, stream>>>(src, dst, cursor, csr, E);

    const int gather_grid = (M * 64 + 255) / 256;       // one wave per node

    // ---- Layer 1 ----
    gemm_kernel<128, 8, 4, true, 1><<<gemm_grid, 256, 0, stream>>>(
        in_feat, wt_p1, nullptr, nullptr, pb1, mbuf, M);
    gather_max_kernel<<<gather_grid, 256, 0, stream>>>(
        (const float2*)mbuf, csr, offsets, counts, (float2*)aggbuf, M);
    gemm_kernel<128, 8, 4, true, 2><<<gemm_grid, 256, 0, stream>>>(
        in_feat, wt_s1, aggbuf, wt_n1, b_sn1, h1buf, M);

    // ---- Layer 2 ----
    gemm_kernel<128, 8, 4, true, 1><<<gemm_grid, 256, 0, stream>>>(
        h1buf, wt_p2, nullptr, nullptr, pb2, mbuf, M);
    gather_max_kernel<<<gather_grid, 256, 0, stream>>>(
        (const float2*)mbuf, csr, offsets, counts, (float2*)aggbuf, M);
    gemm_kernel<40, 5, 2, false, 2><<<gemm_grid, 256, 0, stream>>>(
        h1buf, wt_s2, aggbuf, wt_n2, b_sn2, out, M);
}

// Round 4
// 524.941 us; speedup vs baseline: 11.5866x; 1.5223x over previous
//
#include <hip/hip_runtime.h>

// GraphSAGE (pool aggregator, 2 layers) on MI355X.
// Round 4: bf16 MFMA GEMMs + bf16 gather.
//   - h @ W^T: MFMA B-fragment wants W[n][k] k-contiguous == row-major W as
//     given -> no transpose, only fp32->bf16 convert in prep
//   - GEMM: 128-row tile, 4 waves x 32 rows, 16x16x32_bf16, LDS rows padded
//     to 136 shorts (stride 68 dwords -> 2-way bank aliasing, free)
//   - activations stored bf16 (RELU'd) -> gather reads halve; packed-u16 max
//   - CSR build unchanged from round 3

#define N_FEAT 128

typedef __attribute__((ext_vector_type(8))) short bf16x8;   // 8 bf16 = 4 VGPRs
typedef __attribute__((ext_vector_type(4))) float f32x4;

static __device__ __forceinline__ unsigned short f2bf(float f) {
    unsigned u = __float_as_uint(f);
    unsigned r = (u + 0x7fffu + ((u >> 16) & 1u)) >> 16;   // RNE
    return (unsigned short)r;
}

// ---------------- prep: weights -> bf16 (no transpose), fused biases ----------------
__global__ void prep_kernel(const float* __restrict__ pw1, const float* __restrict__ sw1,
                            const float* __restrict__ nw1, const float* __restrict__ pw2,
                            const float* __restrict__ sw2, const float* __restrict__ nw2,
                            const float* __restrict__ sb1, const float* __restrict__ nb1,
                            const float* __restrict__ sb2, const float* __restrict__ nb2,
                            unsigned short* __restrict__ wb_p1, unsigned short* __restrict__ wb_s1,
                            unsigned short* __restrict__ wb_n1, unsigned short* __restrict__ wb_p2,
                            unsigned short* __restrict__ wb_s2, unsigned short* __restrict__ wb_n2,
                            float* __restrict__ b_sn1, float* __restrict__ b_sn2)
{
    int t = blockIdx.x * 256 + threadIdx.x;
    if (t < 16384) {
        wb_p1[t] = f2bf(pw1[t]);
        wb_s1[t] = f2bf(sw1[t]);
        wb_n1[t] = f2bf(nw1[t]);
        wb_p2[t] = f2bf(pw2[t]);
    }
    if (t < 6144) {                       // 48x128, rows 40..47 zero-padded
        int row = t >> 7;
        wb_s2[t] = (row < 40) ? f2bf(sw2[t]) : 0;
        wb_n2[t] = (row < 40) ? f2bf(nw2[t]) : 0;
    }
    if (t < 128) b_sn1[t] = sb1[t] + nb1[t];
    if (t < 64)  b_sn2[t] = (t < 40) ? (sb2[t] + nb2[t]) : 0.f;
}

__global__ void f2b_kernel(const float4* __restrict__ in, ushort4* __restrict__ out, int n)
{
    int i = blockIdx.x * 256 + threadIdx.x;
    if (i < n) {
        float4 v = in[i];
        ushort4 o;
        o.x = f2bf(v.x); o.y = f2bf(v.y); o.z = f2bf(v.z); o.w = f2bf(v.w);
        out[i] = o;
    }
}

__global__ void zero_int_kernel(int4* __restrict__ p, int n4)
{
    int i = blockIdx.x * 256 + threadIdx.x;
    if (i < n4) p[i] = make_int4(0, 0, 0, 0);
}

// ---------------- CSR build (by dst) — unchanged ----------------
__global__ void hist_kernel(const int* __restrict__ dst, int* __restrict__ counts, int E)
{
    int e = blockIdx.x * 256 + threadIdx.x;
    if (e < E) atomicAdd(&counts[dst[e]], 1);
}

__global__ __launch_bounds__(256) void scan1_kernel(const int* __restrict__ counts,
                                                    int* __restrict__ part,
                                                    int* __restrict__ bsums, int Nn)
{
    __shared__ int sh[256];
    int t = threadIdx.x;
    int base = blockIdx.x * 1024 + t * 4;
    int v[4];
#pragma unroll
    for (int k = 0; k < 4; k++) v[k] = (base + k < Nn) ? counts[base + k] : 0;
    int s = v[0] + v[1] + v[2] + v[3];
    sh[t] = s;
    __syncthreads();
    for (int off = 1; off < 256; off <<= 1) {
        int x = (t >= off) ? sh[t - off] : 0;
        __syncthreads();
        sh[t] += x;
        __syncthreads();
    }
    int run = sh[t] - s;
#pragma unroll
    for (int k = 0; k < 4; k++) {
        if (base + k < Nn) part[base + k] = run;
        run += v[k];
    }
    if (t == 255) bsums[blockIdx.x] = sh[255];
}

__global__ __launch_bounds__(128) void scan2_kernel(int* __restrict__ bsums, int nb)
{
    __shared__ int sh[128];
    int t = threadIdx.x;
    int v = (t < nb) ? bsums[t] : 0;
    sh[t] = v;
    __syncthreads();
    for (int off = 1; off < 128; off <<= 1) {
        int x = (t >= off) ? sh[t - off] : 0;
        __syncthreads();
        sh[t] += x;
        __syncthreads();
    }
    if (t < nb) bsums[t] = sh[t] - v;
}

__global__ void scan3_kernel(const int* __restrict__ part, const int* __restrict__ bsums,
                             int* __restrict__ offsets, int* __restrict__ cursor, int Nn)
{
    int i = blockIdx.x * 256 + threadIdx.x;
    if (i < Nn) {
        int o = part[i] + bsums[i >> 10];
        offsets[i] = o;
        cursor[i] = o;
    }
}

__global__ void scatter_csr_kernel(const int* __restrict__ src, const int* __restrict__ dst,
                                   int* __restrict__ cursor, int* __restrict__ csr, int E)
{
    int e = blockIdx.x * 256 + threadIdx.x;
    if (e < E) {
        int p = atomicAdd(&cursor[dst[e]], 1);
        csr[p] = src[e];
    }
}

// ---------------- pull gather-max, bf16 rows (256 B) ----------------
// One wave per node; lane owns 2 bf16 (one u32). Values are post-ReLU bf16
// (non-negative) -> packed u16 unsigned max == float max; acc=0 start matches
// where(isfinite(segment_max), ., 0).
__global__ __launch_bounds__(256) void gather_max_kernel(
    const unsigned* __restrict__ m4, const int* __restrict__ csr,
    const int* __restrict__ offsets, const int* __restrict__ counts,
    unsigned* __restrict__ agg4, int Nn)
{
    int wid = (blockIdx.x * 256 + threadIdx.x) >> 6;
    int lane = threadIdx.x & 63;
    if (wid >= Nn) return;
    int start = offsets[wid];
    int deg = counts[wid];
    unsigned lo = 0, hi = 0;
    for (int j0 = 0; j0 < deg; j0 += 64) {
        int nb = deg - j0;
        if (nb > 64) nb = 64;
        int sl = csr[start + j0 + (lane < nb ? lane : nb - 1)];
        int j = 0;
        for (; j + 4 <= nb; j += 4) {
            int s0 = __shfl(sl, j + 0), s1 = __shfl(sl, j + 1);
            int s2 = __shfl(sl, j + 2), s3 = __shfl(sl, j + 3);
            unsigned v0 = m4[(size_t)s0 * 64 + lane];
            unsigned v1 = m4[(size_t)s1 * 64 + lane];
            unsigned v2 = m4[(size_t)s2 * 64 + lane];
            unsigned v3 = m4[(size_t)s3 * 64 + lane];
            unsigned a = v0 & 0xffffu, b = v0 & 0xffff0000u;
            unsigned c = v1 & 0xffffu, d = v1 & 0xffff0000u;
            a = a > (v2 & 0xffffu) ? a : (v2 & 0xffffu);
            b = b > (v2 & 0xffff0000u) ? b : (v2 & 0xffff0000u);
            c = c > (v3 & 0xffffu) ? c : (v3 & 0xffffu);
            d = d > (v3 & 0xffff0000u) ? d : (v3 & 0xffff0000u);
            a = a > c ? a : c;
            b = b > d ? b : d;
            lo = lo > a ? lo : a;
            hi = hi > b ? hi : b;
        }
        for (; j < nb; j++) {
            int s = __shfl(sl, j);
            unsigned v = m4[(size_t)s * 64 + lane];
            unsigned a = v & 0xffffu, b = v & 0xffff0000u;
            lo = lo > a ? lo : a;
            hi = hi > b ? hi : b;
        }
    }
    agg4[(size_t)wid * 64 + lane] = lo | hi;
}

// ---------------- bf16 MFMA GEMM ----------------
// C[M,Nout] = act( sum_p A_p[M,128] @ B_p[Nout,128]^T + bias )
// A,B bf16 row-major. 256 thr = 4 waves; wave w owns rows [w*32, w*32+32) of
// the 128-row tile; 16x16x32_bf16; NT col-tiles of 16.
template<int NT, bool RELU, int NPAIRS, bool F32OUT>
__global__ __launch_bounds__(256, 2) void mfma_gemm_kernel(
    const unsigned short* __restrict__ A0, const unsigned short* __restrict__ B0,
    const unsigned short* __restrict__ A1, const unsigned short* __restrict__ B1,
    const float* __restrict__ bias, void* __restrict__ Cout, int M, int Nout)
{
    constexpr int NR = NT * 16;
    __shared__ unsigned short As[128 * 136];   // row stride 136 shorts (68 dwords)
    __shared__ unsigned short Bs[NR * 136];
    __shared__ float BsF[NR];

    const int tid = threadIdx.x;
    const int w = tid >> 6, lane = tid & 63;
    const int q = lane >> 4, r16 = lane & 15;
    const int m0 = blockIdx.x * 128;

    if (tid < NR) BsF[tid] = (tid < Nout) ? bias[tid] : 0.f;

    f32x4 acc[2][NT];
#pragma unroll
    for (int i = 0; i < 2; i++)
#pragma unroll
        for (int j = 0; j < NT; j++) acc[i][j] = (f32x4){0.f, 0.f, 0.f, 0.f};

    for (int p = 0; p < NPAIRS; p++) {
        const unsigned short* __restrict__ A = p ? A1 : A0;
        const unsigned short* __restrict__ B = p ? B1 : B0;
        if (p) __syncthreads();                     // previous pair's LDS consumed
        // stage A tile: 128 rows x 256 B, coalesced 16B chunks
#pragma unroll
        for (int i = 0; i < 8; i++) {
            int j = tid + i * 256;                  // 0..2047
            int row = j >> 4, c = j & 15;
            int grow = m0 + row; if (grow >= M) grow = M - 1;
            uint4 v = *(const uint4*)&A[(size_t)grow * 128 + c * 8];
            *(uint4*)&As[row * 136 + c * 8] = v;
        }
        // stage B: NR rows x 256 B
        for (int j = tid; j < NR * 16; j += 256) {
            int row = j >> 4, c = j & 15;
            uint4 v = *(const uint4*)&B[(size_t)row * 128 + c * 8];
            *(uint4*)&Bs[row * 136 + c * 8] = v;
        }
        __syncthreads();

#pragma unroll
        for (int k0 = 0; k0 < 128; k0 += 32) {
            bf16x8 af[2];
#pragma unroll
            for (int rt = 0; rt < 2; rt++)
                af[rt] = *(const bf16x8*)&As[(w * 32 + rt * 16 + r16) * 136 + k0 + q * 8];
#pragma unroll
            for (int ct = 0; ct < NT; ct++) {
                bf16x8 bfr = *(const bf16x8*)&Bs[(ct * 16 + r16) * 136 + k0 + q * 8];
#pragma unroll
                for (int rt = 0; rt < 2; rt++)
                    acc[rt][ct] = __builtin_amdgcn_mfma_f32_16x16x32_bf16(
                        af[rt], bfr, acc[rt][ct], 0, 0, 0);
            }
        }
    }

    // epilogue: C/D layout col=lane&15, row=(lane>>4)*4+reg
#pragma unroll
    for (int rt = 0; rt < 2; rt++) {
#pragma unroll
        for (int ct = 0; ct < NT; ct++) {
            int col = ct * 16 + r16;
#pragma unroll
            for (int r = 0; r < 4; r++) {
                int grow = m0 + w * 32 + rt * 16 + q * 4 + r;
                float v = acc[rt][ct][r] + BsF[col];
                if (RELU) v = fmaxf(v, 0.f);
                if (grow < M && col < Nout) {
                    if (F32OUT)
                        ((float*)Cout)[(size_t)grow * Nout + col] = v;
                    else
                        ((unsigned short*)Cout)[(size_t)grow * Nout + col] = f2bf(v);
                }
            }
        }
    }
}

extern "C" void kernel_launch(void* const* d_in, const int* in_sizes, int n_in,
                              void* d_out, int out_size, void* d_ws, size_t ws_size,
                              hipStream_t stream)
{
    const float* in_feat = (const float*)d_in[0];
    const int*   src     = (const int*)d_in[1];
    const int*   dst     = (const int*)d_in[2];
    const float* pw1 = (const float*)d_in[3];  const float* pb1 = (const float*)d_in[4];
    const float* sw1 = (const float*)d_in[5];  const float* sb1 = (const float*)d_in[6];
    const float* nw1 = (const float*)d_in[7];  const float* nb1 = (const float*)d_in[8];
    const float* pw2 = (const float*)d_in[9];  const float* pb2 = (const float*)d_in[10];
    const float* sw2 = (const float*)d_in[11]; const float* sb2 = (const float*)d_in[12];
    const float* nw2 = (const float*)d_in[13]; const float* nb2 = (const float*)d_in[14];
    float* out = (float*)d_out;

    const int M = in_sizes[0] / N_FEAT;   // 100000 nodes
    const int E = in_sizes[1];            // 1600000 edges

    // ---- workspace layout (256B-aligned regions) ----
    char* base = (char*)d_ws;
    size_t off = 0;
    auto alloc = [&](size_t bytes) { char* p = base + off; off = (off + bytes + 255) & ~(size_t)255; return p; };
    unsigned short* wb_p1 = (unsigned short*)alloc(16384 * 2);
    unsigned short* wb_s1 = (unsigned short*)alloc(16384 * 2);
    unsigned short* wb_n1 = (unsigned short*)alloc(16384 * 2);
    unsigned short* wb_p2 = (unsigned short*)alloc(16384 * 2);
    unsigned short* wb_s2 = (unsigned short*)alloc(6144 * 2);
    unsigned short* wb_n2 = (unsigned short*)alloc(6144 * 2);
    float* b_sn1 = (float*)alloc(128 * 4);
    float* b_sn2 = (float*)alloc(64 * 4);
    unsigned short* in_b = (unsigned short*)alloc((size_t)M * 128 * 2);
    unsigned short* mb   = (unsigned short*)alloc((size_t)M * 128 * 2);
    unsigned short* agg  = (unsigned short*)alloc((size_t)M * 128 * 2);
    unsigned short* h1   = (unsigned short*)alloc((size_t)M * 128 * 2);
    int* counts  = (int*)alloc((size_t)M * 4);
    int* part    = (int*)alloc((size_t)M * 4);
    int* offsets = (int*)alloc((size_t)M * 4);
    int* cursor  = (int*)alloc((size_t)M * 4);
    int* bsums   = (int*)alloc(128 * 4);
    int* csr     = (int*)alloc((size_t)E * 4);

    const int gemm_grid = (M + 127) / 128;              // 782
    const int edge_grid = (E + 255) / 256;
    const int scan_blocks = (M + 1023) / 1024;          // 98
    const int gather_grid = (M * 64 + 255) / 256;       // one wave per node
    const int nf4 = M * 128 / 4;

    prep_kernel<<<64, 256, 0, stream>>>(pw1, sw1, nw1, pw2, sw2, nw2,
                                        sb1, nb1, sb2, nb2,
                                        wb_p1, wb_s1, wb_n1, wb_p2, wb_s2, wb_n2,
                                        b_sn1, b_sn2);
    f2b_kernel<<<(nf4 + 255) / 256, 256, 0, stream>>>((const float4*)in_feat, (ushort4*)in_b, nf4);

    // ---- CSR build (once; dst identical for both layers) ----
    zero_int_kernel<<<(M / 4 + 255) / 256, 256, 0, stream>>>((int4*)counts, M / 4);
    hist_kernel<<<edge_grid, 256, 0, stream>>>(dst, counts, E);
    scan1_kernel<<<scan_blocks, 256, 0, stream>>>(counts, part, bsums, M);
    scan2_kernel<<<1, 128, 0, stream>>>(bsums, scan_blocks);
    scan3_kernel<<<(M + 255) / 256, 256, 0, stream>>>(part, bsums, offsets, cursor, M);
    scatter_csr_kernel<<<edge_grid, 256, 0, stream>>>(src, dst, cursor, csr, E);

    // ---- Layer 1 ----
    mfma_gemm_kernel<8, true, 1, false><<<gemm_grid, 256, 0, stream>>>(
        in_b, wb_p1, nullptr, nullptr, pb1, mb, M, 128);
    gather_max_kernel<<<gather_grid, 256, 0, stream>>>(
        (const unsigned*)mb, csr, offsets, counts, (unsigned*)agg, M);
    mfma_gemm_kernel<8, true, 2, false><<<gemm_grid, 256, 0, stream>>>(
        in_b, wb_s1, agg, wb_n1, b_sn1, h1, M, 128);

    // ---- Layer 2 ----
    mfma_gemm_kernel<8, true, 1, false><<<gemm_grid, 256, 0, stream>>>(
        h1, wb_p2, nullptr, nullptr, pb2, mb, M, 128);
    gather_max_kernel<<<gather_grid, 256, 0, stream>>>(
        (const unsigned*)mb, csr, offsets, counts, (unsigned*)agg, M);
    mfma_gemm_kernel<3, false, 2, true><<<gemm_grid, 256, 0, stream>>>(
        h1, wb_s2, agg, wb_n2, b_sn2, out, M, 40);
}

// Round 5
// 432.130 us; speedup vs baseline: 14.0751x; 1.2148x over previous
//
#include <hip/hip_runtime.h>

// GraphSAGE (pool aggregator, 2 layers) on MI355X.
// Round 5: kill scatter_csr line-bouncing (105 MB HBM writes for 6.4 MB of
// payload = one 64B line writeback per 4B store, cross-XCD). Two-level
// XCD-local binning:
//   bin_count   per-wg LDS hist over 98 dst-buckets (1024 nodes each)
//   bin_scan    one-wg exclusive scan of 25088 (bucket,wg) counts
//   bin_scatter LDS cursors, zero global atomics; each wg owns 98 private
//               sequential streams -> every line written by one CU only
//   csr_build   one wg per bucket: LDS degree count + LDS scan emits
//               counts/offsets directly (bucket-major == node-major), LDS-
//               atomic scatter into the bucket's private 65 KB csr region.
// Deletes: global hist, zero, scan1/2/3, scatter_csr.
// GEMM (bf16 MFMA) / gather (packed-u16 max) unchanged from round 4.

#define N_FEAT 128
#define NWG_A 256
#define BSHIFT 10            // 1024 nodes per bucket
#define NBMAX 128

typedef __attribute__((ext_vector_type(8))) short bf16x8;   // 8 bf16 = 4 VGPRs
typedef __attribute__((ext_vector_type(4))) float f32x4;

static __device__ __forceinline__ unsigned short f2bf(float f) {
    unsigned u = __float_as_uint(f);
    unsigned r = (u + 0x7fffu + ((u >> 16) & 1u)) >> 16;   // RNE
    return (unsigned short)r;
}

// ---------------- prep: weights -> bf16 (no transpose), fused biases ----------------
__global__ void prep_kernel(const float* __restrict__ pw1, const float* __restrict__ sw1,
                            const float* __restrict__ nw1, const float* __restrict__ pw2,
                            const float* __restrict__ sw2, const float* __restrict__ nw2,
                            const float* __restrict__ sb1, const float* __restrict__ nb1,
                            const float* __restrict__ sb2, const float* __restrict__ nb2,
                            unsigned short* __restrict__ wb_p1, unsigned short* __restrict__ wb_s1,
                            unsigned short* __restrict__ wb_n1, unsigned short* __restrict__ wb_p2,
                            unsigned short* __restrict__ wb_s2, unsigned short* __restrict__ wb_n2,
                            float* __restrict__ b_sn1, float* __restrict__ b_sn2)
{
    int t = blockIdx.x * 256 + threadIdx.x;
    if (t < 16384) {
        wb_p1[t] = f2bf(pw1[t]);
        wb_s1[t] = f2bf(sw1[t]);
        wb_n1[t] = f2bf(nw1[t]);
        wb_p2[t] = f2bf(pw2[t]);
    }
    if (t < 6144) {                       // 48x128, rows 40..47 zero-padded
        int row = t >> 7;
        wb_s2[t] = (row < 40) ? f2bf(sw2[t]) : 0;
        wb_n2[t] = (row < 40) ? f2bf(nw2[t]) : 0;
    }
    if (t < 128) b_sn1[t] = sb1[t] + nb1[t];
    if (t < 64)  b_sn2[t] = (t < 40) ? (sb2[t] + nb2[t]) : 0.f;
}

__global__ void f2b_kernel(const float4* __restrict__ in, ushort4* __restrict__ out, int n)
{
    int i = blockIdx.x * 256 + threadIdx.x;
    if (i < n) {
        float4 v = in[i];
        ushort4 o;
        o.x = f2bf(v.x); o.y = f2bf(v.y); o.z = f2bf(v.z); o.w = f2bf(v.w);
        out[i] = o;
    }
}

// ---------------- CSR build: two-level XCD-local binning ----------------

// Phase A1: per-wg bucket histogram (LDS), layout bucket-major wgcnt[b*NWG_A+wg]
__global__ __launch_bounds__(256) void bin_count_kernel(const int* __restrict__ dst,
                                                        int* __restrict__ wgcnt,
                                                        int E, int NB)
{
    __shared__ int cnt[NBMAX];
    const int wg = blockIdx.x, tid = threadIdx.x;
    if (tid < NB) cnt[tid] = 0;
    __syncthreads();
    const int slab = (E + NWG_A - 1) / NWG_A;
    const int e0 = wg * slab;
    const int e1 = min(e0 + slab, E);
    for (int e = e0 + tid; e < e1; e += 256)
        atomicAdd(&cnt[dst[e] >> BSHIFT], 1);
    __syncthreads();
    if (tid < NB) wgcnt[tid * NWG_A + wg] = cnt[tid];
}

// Phase A2: one-wg exclusive scan of NB*NWG_A counts; sentinel total at end.
__global__ __launch_bounds__(256) void bin_scan_kernel(const int* __restrict__ wgcnt,
                                                       int* __restrict__ binoff, int NB)
{
    __shared__ int sh[256];
    const int t = threadIdx.x;
    const int base = t * NB;                 // 256 threads x NB = NB*NWG_A
    int s = 0;
    for (int k = 0; k < NB; k++) s += wgcnt[base + k];
    sh[t] = s;
    __syncthreads();
    for (int off = 1; off < 256; off <<= 1) {
        int x = (t >= off) ? sh[t - off] : 0;
        __syncthreads();
        sh[t] += x;
        __syncthreads();
    }
    int run = sh[t] - s;
    for (int k = 0; k < NB; k++) {
        int v = wgcnt[base + k];
        binoff[base + k] = run;
        run += v;
    }
    if (t == 255) binoff[NB * NWG_A] = run;  // == E
}

// Phase A3: scatter packed (dst_local<<17)|src into private per-(wg,bucket)
// streams. LDS cursors -> no global atomics; streams exclusively owned.
__global__ __launch_bounds__(256) void bin_scatter_kernel(const int* __restrict__ src,
                                                          const int* __restrict__ dst,
                                                          const int* __restrict__ binoff,
                                                          unsigned* __restrict__ binned,
                                                          int E, int NB)
{
    __shared__ int cur[NBMAX];
    const int wg = blockIdx.x, tid = threadIdx.x;
    if (tid < NB) cur[tid] = binoff[tid * NWG_A + wg];
    __syncthreads();
    const int slab = (E + NWG_A - 1) / NWG_A;
    const int e0 = wg * slab;
    const int e1 = min(e0 + slab, E);
    for (int e = e0 + tid; e < e1; e += 256) {
        int d = dst[e];
        int b = d >> BSHIFT;
        unsigned rec = ((unsigned)(d & ((1 << BSHIFT) - 1)) << 17) | (unsigned)src[e];
        int p = atomicAdd(&cur[b], 1);
        binned[p] = rec;
    }
}

// Phase B: one wg per bucket. LDS degree hist + LDS scan -> counts/offsets
// (bucket-major csr order == node order, so no global hist/scan needed),
// then LDS-atomic scatter of src into the bucket's private csr region.
__global__ __launch_bounds__(256) void csr_build_kernel(const unsigned* __restrict__ binned,
                                                        const int* __restrict__ binoff,
                                                        int* __restrict__ csr,
                                                        int* __restrict__ offsets,
                                                        int* __restrict__ counts, int M)
{
    __shared__ int cnt[1 << BSHIFT];
    __shared__ int scn[1 << BSHIFT];
    __shared__ int sh[256];
    const int b = blockIdx.x, t = threadIdx.x;
    const int rs = binoff[b * NWG_A];
    const int re = binoff[(b + 1) * NWG_A];      // last bucket reads sentinel

    for (int j = t; j < (1 << BSHIFT); j += 256) cnt[j] = 0;
    __syncthreads();
    for (int i = rs + t; i < re; i += 256)
        atomicAdd(&cnt[binned[i] >> 17], 1);
    __syncthreads();

    // exclusive scan of 1024 counts, 4 per thread
    const int base4 = t * 4;
    int v[4];
#pragma unroll
    for (int k = 0; k < 4; k++) v[k] = cnt[base4 + k];
    int s = v[0] + v[1] + v[2] + v[3];
    sh[t] = s;
    __syncthreads();
    for (int off = 1; off < 256; off <<= 1) {
        int x = (t >= off) ? sh[t - off] : 0;
        __syncthreads();
        sh[t] += x;
        __syncthreads();
    }
    int run = sh[t] - s;
#pragma unroll
    for (int k = 0; k < 4; k++) {
        scn[base4 + k] = run;
        run += v[k];
    }

    const int node0 = b << BSHIFT;
#pragma unroll
    for (int k = 0; k < 4; k++) {
        int j = base4 + k;
        int node = node0 + j;
        if (node < M) {
            counts[node] = v[k];
            offsets[node] = rs + scn[j];
        }
    }
    __syncthreads();                             // all scn final before atomics

    for (int i = rs + t; i < re; i += 256) {
        unsigned r = binned[i];
        int p = atomicAdd(&scn[r >> 17], 1);
        csr[rs + p] = (int)(r & 0x1FFFFu);
    }
}

// ---------------- pull gather-max, bf16 rows (256 B) ----------------
__global__ __launch_bounds__(256) void gather_max_kernel(
    const unsigned* __restrict__ m4, const int* __restrict__ csr,
    const int* __restrict__ offsets, const int* __restrict__ counts,
    unsigned* __restrict__ agg4, int Nn)
{
    int wid = (blockIdx.x * 256 + threadIdx.x) >> 6;
    int lane = threadIdx.x & 63;
    if (wid >= Nn) return;
    int start = offsets[wid];
    int deg = counts[wid];
    unsigned lo = 0, hi = 0;
    for (int j0 = 0; j0 < deg; j0 += 64) {
        int nb = deg - j0;
        if (nb > 64) nb = 64;
        int sl = csr[start + j0 + (lane < nb ? lane : nb - 1)];
        int j = 0;
        for (; j + 4 <= nb; j += 4) {
            int s0 = __shfl(sl, j + 0), s1 = __shfl(sl, j + 1);
            int s2 = __shfl(sl, j + 2), s3 = __shfl(sl, j + 3);
            unsigned v0 = m4[(size_t)s0 * 64 + lane];
            unsigned v1 = m4[(size_t)s1 * 64 + lane];
            unsigned v2 = m4[(size_t)s2 * 64 + lane];
            unsigned v3 = m4[(size_t)s3 * 64 + lane];
            unsigned a = v0 & 0xffffu, b = v0 & 0xffff0000u;
            unsigned c = v1 & 0xffffu, d = v1 & 0xffff0000u;
            a = a > (v2 & 0xffffu) ? a : (v2 & 0xffffu);
            b = b > (v2 & 0xffff0000u) ? b : (v2 & 0xffff0000u);
            c = c > (v3 & 0xffffu) ? c : (v3 & 0xffffu);
            d = d > (v3 & 0xffff0000u) ? d : (v3 & 0xffff0000u);
            a = a > c ? a : c;
            b = b > d ? b : d;
            lo = lo > a ? lo : a;
            hi = hi > b ? hi : b;
        }
        for (; j < nb; j++) {
            int s = __shfl(sl, j);
            unsigned v = m4[(size_t)s * 64 + lane];
            unsigned a = v & 0xffffu, b = v & 0xffff0000u;
            lo = lo > a ? lo : a;
            hi = hi > b ? hi : b;
        }
    }
    agg4[(size_t)wid * 64 + lane] = lo | hi;
}

// ---------------- bf16 MFMA GEMM (unchanged from round 4) ----------------
template<int NT, bool RELU, int NPAIRS, bool F32OUT>
__global__ __launch_bounds__(256, 2) void mfma_gemm_kernel(
    const unsigned short* __restrict__ A0, const unsigned short* __restrict__ B0,
    const unsigned short* __restrict__ A1, const unsigned short* __restrict__ B1,
    const float* __restrict__ bias, void* __restrict__ Cout, int M, int Nout)
{
    constexpr int NR = NT * 16;
    __shared__ unsigned short As[128 * 136];   // row stride 136 shorts (68 dwords)
    __shared__ unsigned short Bs[NR * 136];
    __shared__ float BsF[NR];

    const int tid = threadIdx.x;
    const int w = tid >> 6, lane = tid & 63;
    const int q = lane >> 4, r16 = lane & 15;
    const int m0 = blockIdx.x * 128;

    if (tid < NR) BsF[tid] = (tid < Nout) ? bias[tid] : 0.f;

    f32x4 acc[2][NT];
#pragma unroll
    for (int i = 0; i < 2; i++)
#pragma unroll
        for (int j = 0; j < NT; j++) acc[i][j] = (f32x4){0.f, 0.f, 0.f, 0.f};

    for (int p = 0; p < NPAIRS; p++) {
        const unsigned short* __restrict__ A = p ? A1 : A0;
        const unsigned short* __restrict__ B = p ? B1 : B0;
        if (p) __syncthreads();
#pragma unroll
        for (int i = 0; i < 8; i++) {
            int j = tid + i * 256;
            int row = j >> 4, c = j & 15;
            int grow = m0 + row; if (grow >= M) grow = M - 1;
            uint4 v = *(const uint4*)&A[(size_t)grow * 128 + c * 8];
            *(uint4*)&As[row * 136 + c * 8] = v;
        }
        for (int j = tid; j < NR * 16; j += 256) {
            int row = j >> 4, c = j & 15;
            uint4 v = *(const uint4*)&B[(size_t)row * 128 + c * 8];
            *(uint4*)&Bs[row * 136 + c * 8] = v;
        }
        __syncthreads();

#pragma unroll
        for (int k0 = 0; k0 < 128; k0 += 32) {
            bf16x8 af[2];
#pragma unroll
            for (int rt = 0; rt < 2; rt++)
                af[rt] = *(const bf16x8*)&As[(w * 32 + rt * 16 + r16) * 136 + k0 + q * 8];
#pragma unroll
            for (int ct = 0; ct < NT; ct++) {
                bf16x8 bfr = *(const bf16x8*)&Bs[(ct * 16 + r16) * 136 + k0 + q * 8];
#pragma unroll
                for (int rt = 0; rt < 2; rt++)
                    acc[rt][ct] = __builtin_amdgcn_mfma_f32_16x16x32_bf16(
                        af[rt], bfr, acc[rt][ct], 0, 0, 0);
            }
        }
    }

#pragma unroll
    for (int rt = 0; rt < 2; rt++) {
#pragma unroll
        for (int ct = 0; ct < NT; ct++) {
            int col = ct * 16 + r16;
#pragma unroll
            for (int r = 0; r < 4; r++) {
                int grow = m0 + w * 32 + rt * 16 + q * 4 + r;
                float v = acc[rt][ct][r] + BsF[col];
                if (RELU) v = fmaxf(v, 0.f);
                if (grow < M && col < Nout) {
                    if (F32OUT)
                        ((float*)Cout)[(size_t)grow * Nout + col] = v;
                    else
                        ((unsigned short*)Cout)[(size_t)grow * Nout + col] = f2bf(v);
                }
            }
        }
    }
}

extern "C" void kernel_launch(void* const* d_in, const int* in_sizes, int n_in,
                              void* d_out, int out_size, void* d_ws, size_t ws_size,
                              hipStream_t stream)
{
    const float* in_feat = (const float*)d_in[0];
    const int*   src     = (const int*)d_in[1];
    const int*   dst     = (const int*)d_in[2];
    const float* pw1 = (const float*)d_in[3];  const float* pb1 = (const float*)d_in[4];
    const float* sw1 = (const float*)d_in[5];  const float* sb1 = (const float*)d_in[6];
    const float* nw1 = (const float*)d_in[7];  const float* nb1 = (const float*)d_in[8];
    const float* pw2 = (const float*)d_in[9];  const float* pb2 = (const float*)d_in[10];
    const float* sw2 = (const float*)d_in[11]; const float* sb2 = (const float*)d_in[12];
    const float* nw2 = (const float*)d_in[13]; const float* nb2 = (const float*)d_in[14];
    float* out = (float*)d_out;

    const int M = in_sizes[0] / N_FEAT;   // 100000 nodes
    const int E = in_sizes[1];            // 1600000 edges
    const int NB = (M + (1 << BSHIFT) - 1) >> BSHIFT;   // 98 buckets

    // ---- workspace layout (256B-aligned regions) ----
    char* base = (char*)d_ws;
    size_t off = 0;
    auto alloc = [&](size_t bytes) { char* p = base + off; off = (off + bytes + 255) & ~(size_t)255; return p; };
    unsigned short* wb_p1 = (unsigned short*)alloc(16384 * 2);
    unsigned short* wb_s1 = (unsigned short*)alloc(16384 * 2);
    unsigned short* wb_n1 = (unsigned short*)alloc(16384 * 2);
    unsigned short* wb_p2 = (unsigned short*)alloc(16384 * 2);
    unsigned short* wb_s2 = (unsigned short*)alloc(6144 * 2);
    unsigned short* wb_n2 = (unsigned short*)alloc(6144 * 2);
    float* b_sn1 = (float*)alloc(128 * 4);
    float* b_sn2 = (float*)alloc(64 * 4);
    unsigned short* in_b = (unsigned short*)alloc((size_t)M * 128 * 2);
    unsigned short* mb   = (unsigned short*)alloc((size_t)M * 128 * 2);
    unsigned short* agg  = (unsigned short*)alloc((size_t)M * 128 * 2);
    unsigned short* h1   = (unsigned short*)alloc((size_t)M * 128 * 2);
    int* counts  = (int*)alloc((size_t)M * 4);
    int* offsets = (int*)alloc((size_t)M * 4);
    int* wgcnt   = (int*)alloc((size_t)NB * NWG_A * 4);
    int* binoff  = (int*)alloc(((size_t)NB * NWG_A + 1) * 4);
    unsigned* binned = (unsigned*)alloc((size_t)E * 4);
    int* csr     = (int*)alloc((size_t)E * 4);

    const int gemm_grid = (M + 127) / 128;
    const int gather_grid = (M * 64 + 255) / 256;       // one wave per node
    const int nf4 = M * 128 / 4;

    prep_kernel<<<64, 256, 0, stream>>>(pw1, sw1, nw1, pw2, sw2, nw2,
                                        sb1, nb1, sb2, nb2,
                                        wb_p1, wb_s1, wb_n1, wb_p2, wb_s2, wb_n2,
                                        b_sn1, b_sn2);
    f2b_kernel<<<(nf4 + 255) / 256, 256, 0, stream>>>((const float4*)in_feat, (ushort4*)in_b, nf4);

    // ---- CSR build: XCD-local two-level binning ----
    bin_count_kernel<<<NWG_A, 256, 0, stream>>>(dst, wgcnt, E, NB);
    bin_scan_kernel<<<1, 256, 0, stream>>>(wgcnt, binoff, NB);
    bin_scatter_kernel<<<NWG_A, 256, 0, stream>>>(src, dst, binoff, binned, E, NB);
    csr_build_kernel<<<NB, 256, 0, stream>>>(binned, binoff, csr, offsets, counts, M);

    // ---- Layer 1 ----
    mfma_gemm_kernel<8, true, 1, false><<<gemm_grid, 256, 0, stream>>>(
        in_b, wb_p1, nullptr, nullptr, pb1, mb, M, 128);
    gather_max_kernel<<<gather_grid, 256, 0, stream>>>(
        (const unsigned*)mb, csr, offsets, counts, (unsigned*)agg, M);
    mfma_gemm_kernel<8, true, 2, false><<<gemm_grid, 256, 0, stream>>>(
        in_b, wb_s1, agg, wb_n1, b_sn1, h1, M, 128);

    // ---- Layer 2 ----
    mfma_gemm_kernel<8, true, 1, false><<<gemm_grid, 256, 0, stream>>>(
        h1, wb_p2, nullptr, nullptr, pb2, mb, M, 128);
    gather_max_kernel<<<gather_grid, 256, 0, stream>>>(
        (const unsigned*)mb, csr, offsets, counts, (unsigned*)agg, M);
    mfma_gemm_kernel<3, false, 2, true><<<gemm_grid, 256, 0, stream>>>(
        h1, wb_s2, agg, wb_n2, b_sn2, out, M, 40);
}

// Round 6
// 412.732 us; speedup vs baseline: 14.7366x; 1.0470x over previous
//
#include <hip/hip_runtime.h>

// GraphSAGE (pool aggregator, 2 layers) on MI355X.
// Round 6:
//   gather_max: 4 rows per load instruction (lane group g=lane>>4 owns row
//     j+g, 16B ushort8 chunk per lane) -> 4x loads in flight; packed
//     v_pk_max_u16 via __builtin_elementwise_max; shfl_xor butterfly merge.
//     Max is idempotent -> tail = clamp row index (duplicates free).
//   mfma_gemm: A fragments have zero cross-lane sharing -> load A direct from
//     global (16B/lane), LDS holds only B (35 KB) -> 4 blocks/CU.
// CSR build (XCD-local two-level binning) unchanged from round 5.

#define N_FEAT 128
#define NWG_A 256
#define BSHIFT 10            // 1024 nodes per bucket
#define NBMAX 128

typedef __attribute__((ext_vector_type(8))) short bf16x8;            // 8 bf16 = 4 VGPRs
typedef __attribute__((ext_vector_type(8))) unsigned short u16x8;    // 16 B
typedef __attribute__((ext_vector_type(4))) float f32x4;

static __device__ __forceinline__ unsigned short f2bf(float f) {
    unsigned u = __float_as_uint(f);
    unsigned r = (u + 0x7fffu + ((u >> 16) & 1u)) >> 16;   // RNE
    return (unsigned short)r;
}

// ---------------- prep: weights -> bf16 (no transpose), fused biases ----------------
__global__ void prep_kernel(const float* __restrict__ pw1, const float* __restrict__ sw1,
                            const float* __restrict__ nw1, const float* __restrict__ pw2,
                            const float* __restrict__ sw2, const float* __restrict__ nw2,
                            const float* __restrict__ sb1, const float* __restrict__ nb1,
                            const float* __restrict__ sb2, const float* __restrict__ nb2,
                            unsigned short* __restrict__ wb_p1, unsigned short* __restrict__ wb_s1,
                            unsigned short* __restrict__ wb_n1, unsigned short* __restrict__ wb_p2,
                            unsigned short* __restrict__ wb_s2, unsigned short* __restrict__ wb_n2,
                            float* __restrict__ b_sn1, float* __restrict__ b_sn2)
{
    int t = blockIdx.x * 256 + threadIdx.x;
    if (t < 16384) {
        wb_p1[t] = f2bf(pw1[t]);
        wb_s1[t] = f2bf(sw1[t]);
        wb_n1[t] = f2bf(nw1[t]);
        wb_p2[t] = f2bf(pw2[t]);
    }
    if (t < 6144) {                       // 48x128, rows 40..47 zero-padded
        int row = t >> 7;
        wb_s2[t] = (row < 40) ? f2bf(sw2[t]) : 0;
        wb_n2[t] = (row < 40) ? f2bf(nw2[t]) : 0;
    }
    if (t < 128) b_sn1[t] = sb1[t] + nb1[t];
    if (t < 64)  b_sn2[t] = (t < 40) ? (sb2[t] + nb2[t]) : 0.f;
}

__global__ void f2b_kernel(const float4* __restrict__ in, ushort4* __restrict__ out, int n)
{
    int i = blockIdx.x * 256 + threadIdx.x;
    if (i < n) {
        float4 v = in[i];
        ushort4 o;
        o.x = f2bf(v.x); o.y = f2bf(v.y); o.z = f2bf(v.z); o.w = f2bf(v.w);
        out[i] = o;
    }
}

// ---------------- CSR build: two-level XCD-local binning (unchanged) ----------------
__global__ __launch_bounds__(256) void bin_count_kernel(const int* __restrict__ dst,
                                                        int* __restrict__ wgcnt,
                                                        int E, int NB)
{
    __shared__ int cnt[NBMAX];
    const int wg = blockIdx.x, tid = threadIdx.x;
    if (tid < NB) cnt[tid] = 0;
    __syncthreads();
    const int slab = (E + NWG_A - 1) / NWG_A;
    const int e0 = wg * slab;
    const int e1 = min(e0 + slab, E);
    for (int e = e0 + tid; e < e1; e += 256)
        atomicAdd(&cnt[dst[e] >> BSHIFT], 1);
    __syncthreads();
    if (tid < NB) wgcnt[tid * NWG_A + wg] = cnt[tid];
}

__global__ __launch_bounds__(256) void bin_scan_kernel(const int* __restrict__ wgcnt,
                                                       int* __restrict__ binoff, int NB)
{
    __shared__ int sh[256];
    const int t = threadIdx.x;
    const int base = t * NB;
    int s = 0;
    for (int k = 0; k < NB; k++) s += wgcnt[base + k];
    sh[t] = s;
    __syncthreads();
    for (int off = 1; off < 256; off <<= 1) {
        int x = (t >= off) ? sh[t - off] : 0;
        __syncthreads();
        sh[t] += x;
        __syncthreads();
    }
    int run = sh[t] - s;
    for (int k = 0; k < NB; k++) {
        int v = wgcnt[base + k];
        binoff[base + k] = run;
        run += v;
    }
    if (t == 255) binoff[NB * NWG_A] = run;  // == E
}

__global__ __launch_bounds__(256) void bin_scatter_kernel(const int* __restrict__ src,
                                                          const int* __restrict__ dst,
                                                          const int* __restrict__ binoff,
                                                          unsigned* __restrict__ binned,
                                                          int E, int NB)
{
    __shared__ int cur[NBMAX];
    const int wg = blockIdx.x, tid = threadIdx.x;
    if (tid < NB) cur[tid] = binoff[tid * NWG_A + wg];
    __syncthreads();
    const int slab = (E + NWG_A - 1) / NWG_A;
    const int e0 = wg * slab;
    const int e1 = min(e0 + slab, E);
    for (int e = e0 + tid; e < e1; e += 256) {
        int d = dst[e];
        int b = d >> BSHIFT;
        unsigned rec = ((unsigned)(d & ((1 << BSHIFT) - 1)) << 17) | (unsigned)src[e];
        int p = atomicAdd(&cur[b], 1);
        binned[p] = rec;
    }
}

__global__ __launch_bounds__(256) void csr_build_kernel(const unsigned* __restrict__ binned,
                                                        const int* __restrict__ binoff,
                                                        int* __restrict__ csr,
                                                        int* __restrict__ offsets,
                                                        int* __restrict__ counts, int M)
{
    __shared__ int cnt[1 << BSHIFT];
    __shared__ int scn[1 << BSHIFT];
    __shared__ int sh[256];
    const int b = blockIdx.x, t = threadIdx.x;
    const int rs = binoff[b * NWG_A];
    const int re = binoff[(b + 1) * NWG_A];

    for (int j = t; j < (1 << BSHIFT); j += 256) cnt[j] = 0;
    __syncthreads();
    for (int i = rs + t; i < re; i += 256)
        atomicAdd(&cnt[binned[i] >> 17], 1);
    __syncthreads();

    const int base4 = t * 4;
    int v[4];
#pragma unroll
    for (int k = 0; k < 4; k++) v[k] = cnt[base4 + k];
    int s = v[0] + v[1] + v[2] + v[3];
    sh[t] = s;
    __syncthreads();
    for (int off = 1; off < 256; off <<= 1) {
        int x = (t >= off) ? sh[t - off] : 0;
        __syncthreads();
        sh[t] += x;
        __syncthreads();
    }
    int run = sh[t] - s;
#pragma unroll
    for (int k = 0; k < 4; k++) {
        scn[base4 + k] = run;
        run += v[k];
    }

    const int node0 = b << BSHIFT;
#pragma unroll
    for (int k = 0; k < 4; k++) {
        int j = base4 + k;
        int node = node0 + j;
        if (node < M) {
            counts[node] = v[k];
            offsets[node] = rs + scn[j];
        }
    }
    __syncthreads();

    for (int i = rs + t; i < re; i += 256) {
        unsigned r = binned[i];
        int p = atomicAdd(&scn[r >> 17], 1);
        csr[rs + p] = (int)(r & 0x1FFFFu);
    }
}

// ---------------- pull gather-max: 4 rows per load instruction ----------------
// One wave per node. Lane group g=lane>>4 owns row j+g of each 4-row batch;
// lane reads the 16B chunk c=lane&15 of that row. Packed u16 max (values are
// post-ReLU bf16, non-negative). Tail: clamp row index (max idempotent).
// Final shfl_xor(16,32) butterfly merges the 4 groups; g==0 lanes store.
__global__ __launch_bounds__(256) void gather_max_kernel(
    const u16x8* __restrict__ m16, const int* __restrict__ csr,
    const int* __restrict__ offsets, const int* __restrict__ counts,
    u16x8* __restrict__ agg16, int Nn)
{
    int wid = (blockIdx.x * 256 + threadIdx.x) >> 6;
    int lane = threadIdx.x & 63;
    if (wid >= Nn) return;
    const int g = lane >> 4, c = lane & 15;
    int start = offsets[wid];
    int deg = counts[wid];
    u16x8 acc = (u16x8){0, 0, 0, 0, 0, 0, 0, 0};
    for (int j0 = 0; j0 < deg; j0 += 64) {
        int nb = deg - j0;
        if (nb > 64) nb = 64;
        int sl = csr[start + j0 + (lane < nb ? lane : nb - 1)];
        for (int j = 0; j < nb; j += 4) {
            int jj = j + g;
            if (jj >= nb) jj = nb - 1;
            int s = __shfl(sl, jj);                         // per-lane index (bpermute)
            u16x8 v = m16[(size_t)s * 16 + c];
            acc = __builtin_elementwise_max(acc, v);
        }
    }
    // merge the 4 lane groups (lanes c, c+16, c+32, c+48)
#pragma unroll
    for (int d = 16; d <= 32; d <<= 1) {
        int4 a = *(int4*)&acc;
        int4 t;
        t.x = __shfl_xor(a.x, d);
        t.y = __shfl_xor(a.y, d);
        t.z = __shfl_xor(a.z, d);
        t.w = __shfl_xor(a.w, d);
        acc = __builtin_elementwise_max(acc, *(u16x8*)&t);
    }
    if (g == 0) agg16[(size_t)wid * 16 + c] = acc;
}

// ---------------- bf16 MFMA GEMM: A direct from global, B-only LDS ----------------
// C[M,Nout] = act( sum_p A_p[M,128] @ B_p[Nout,128]^T + bias )
// 256 thr = 4 waves; wave w owns rows [w*32, w*32+32); 16x16x32_bf16.
template<int NT, bool RELU, int NPAIRS, bool F32OUT>
__global__ __launch_bounds__(256, 4) void mfma_gemm_kernel(
    const unsigned short* __restrict__ A0, const unsigned short* __restrict__ B0,
    const unsigned short* __restrict__ A1, const unsigned short* __restrict__ B1,
    const float* __restrict__ bias, void* __restrict__ Cout, int M, int Nout)
{
    constexpr int NR = NT * 16;
    __shared__ unsigned short Bs[NR * 136];    // row stride 136 shorts
    __shared__ float BsF[NR];

    const int tid = threadIdx.x;
    const int w = tid >> 6, lane = tid & 63;
    const int q = lane >> 4, r16 = lane & 15;
    const int m0 = blockIdx.x * 128;

    if (tid < NR) BsF[tid] = (tid < Nout) ? bias[tid] : 0.f;

    // this lane's two A-fragment rows (clamped; stores are guarded)
    int rowA[2];
#pragma unroll
    for (int rt = 0; rt < 2; rt++) {
        int r = m0 + w * 32 + rt * 16 + r16;
        rowA[rt] = r < M ? r : (M - 1);
    }

    f32x4 acc[2][NT];
#pragma unroll
    for (int i = 0; i < 2; i++)
#pragma unroll
        for (int j = 0; j < NT; j++) acc[i][j] = (f32x4){0.f, 0.f, 0.f, 0.f};

    for (int p = 0; p < NPAIRS; p++) {
        const unsigned short* __restrict__ A = p ? A1 : A0;
        const unsigned short* __restrict__ B = p ? B1 : B0;
        if (p) __syncthreads();                // previous pair's Bs consumed
        for (int j = tid; j < NR * 16; j += 256) {
            int row = j >> 4, cc = j & 15;
            uint4 v = *(const uint4*)&B[(size_t)row * 128 + cc * 8];
            *(uint4*)&Bs[row * 136 + cc * 8] = v;
        }
        __syncthreads();

#pragma unroll
        for (int k0 = 0; k0 < 128; k0 += 32) {
            bf16x8 af[2];
#pragma unroll
            for (int rt = 0; rt < 2; rt++)
                af[rt] = *(const bf16x8*)&A[(size_t)rowA[rt] * 128 + k0 + q * 8];
#pragma unroll
            for (int ct = 0; ct < NT; ct++) {
                bf16x8 bfr = *(const bf16x8*)&Bs[(ct * 16 + r16) * 136 + k0 + q * 8];
#pragma unroll
                for (int rt = 0; rt < 2; rt++)
                    acc[rt][ct] = __builtin_amdgcn_mfma_f32_16x16x32_bf16(
                        af[rt], bfr, acc[rt][ct], 0, 0, 0);
            }
        }
    }

    // epilogue: C/D layout col=lane&15, row=(lane>>4)*4+reg
#pragma unroll
    for (int rt = 0; rt < 2; rt++) {
#pragma unroll
        for (int ct = 0; ct < NT; ct++) {
            int col = ct * 16 + r16;
#pragma unroll
            for (int r = 0; r < 4; r++) {
                int grow = m0 + w * 32 + rt * 16 + q * 4 + r;
                float v = acc[rt][ct][r] + BsF[col];
                if (RELU) v = fmaxf(v, 0.f);
                if (grow < M && col < Nout) {
                    if (F32OUT)
                        ((float*)Cout)[(size_t)grow * Nout + col] = v;
                    else
                        ((unsigned short*)Cout)[(size_t)grow * Nout + col] = f2bf(v);
                }
            }
        }
    }
}

extern "C" void kernel_launch(void* const* d_in, const int* in_sizes, int n_in,
                              void* d_out, int out_size, void* d_ws, size_t ws_size,
                              hipStream_t stream)
{
    const float* in_feat = (const float*)d_in[0];
    const int*   src     = (const int*)d_in[1];
    const int*   dst     = (const int*)d_in[2];
    const float* pw1 = (const float*)d_in[3];  const float* pb1 = (const float*)d_in[4];
    const float* sw1 = (const float*)d_in[5];  const float* sb1 = (const float*)d_in[6];
    const float* nw1 = (const float*)d_in[7];  const float* nb1 = (const float*)d_in[8];
    const float* pw2 = (const float*)d_in[9];  const float* pb2 = (const float*)d_in[10];
    const float* sw2 = (const float*)d_in[11]; const float* sb2 = (const float*)d_in[12];
    const float* nw2 = (const float*)d_in[13]; const float* nb2 = (const float*)d_in[14];
    float* out = (float*)d_out;

    const int M = in_sizes[0] / N_FEAT;   // 100000 nodes
    const int E = in_sizes[1];            // 1600000 edges
    const int NB = (M + (1 << BSHIFT) - 1) >> BSHIFT;   // 98 buckets

    // ---- workspace layout (256B-aligned regions) ----
    char* base = (char*)d_ws;
    size_t off = 0;
    auto alloc = [&](size_t bytes) { char* p = base + off; off = (off + bytes + 255) & ~(size_t)255; return p; };
    unsigned short* wb_p1 = (unsigned short*)alloc(16384 * 2);
    unsigned short* wb_s1 = (unsigned short*)alloc(16384 * 2);
    unsigned short* wb_n1 = (unsigned short*)alloc(16384 * 2);
    unsigned short* wb_p2 = (unsigned short*)alloc(16384 * 2);
    unsigned short* wb_s2 = (unsigned short*)alloc(6144 * 2);
    unsigned short* wb_n2 = (unsigned short*)alloc(6144 * 2);
    float* b_sn1 = (float*)alloc(128 * 4);
    float* b_sn2 = (float*)alloc(64 * 4);
    unsigned short* in_b = (unsigned short*)alloc((size_t)M * 128 * 2);
    unsigned short* mb   = (unsigned short*)alloc((size_t)M * 128 * 2);
    unsigned short* agg  = (unsigned short*)alloc((size_t)M * 128 * 2);
    unsigned short* h1   = (unsigned short*)alloc((size_t)M * 128 * 2);
    int* counts  = (int*)alloc((size_t)M * 4);
    int* offsets = (int*)alloc((size_t)M * 4);
    int* wgcnt   = (int*)alloc((size_t)NB * NWG_A * 4);
    int* binoff  = (int*)alloc(((size_t)NB * NWG_A + 1) * 4);
    unsigned* binned = (unsigned*)alloc((size_t)E * 4);
    int* csr     = (int*)alloc((size_t)E * 4);

    const int gemm_grid = (M + 127) / 128;
    const int gather_grid = (M * 64 + 255) / 256;       // one wave per node
    const int nf4 = M * 128 / 4;

    prep_kernel<<<64, 256, 0, stream>>>(pw1, sw1, nw1, pw2, sw2, nw2,
                                        sb1, nb1, sb2, nb2,
                                        wb_p1, wb_s1, wb_n1, wb_p2, wb_s2, wb_n2,
                                        b_sn1, b_sn2);
    f2b_kernel<<<(nf4 + 255) / 256, 256, 0, stream>>>((const float4*)in_feat, (ushort4*)in_b, nf4);

    // ---- CSR build: XCD-local two-level binning ----
    bin_count_kernel<<<NWG_A, 256, 0, stream>>>(dst, wgcnt, E, NB);
    bin_scan_kernel<<<1, 256, 0, stream>>>(wgcnt, binoff, NB);
    bin_scatter_kernel<<<NWG_A, 256, 0, stream>>>(src, dst, binoff, binned, E, NB);
    csr_build_kernel<<<NB, 256, 0, stream>>>(binned, binoff, csr, offsets, counts, M);

    // ---- Layer 1 ----
    mfma_gemm_kernel<8, true, 1, false><<<gemm_grid, 256, 0, stream>>>(
        in_b, wb_p1, nullptr, nullptr, pb1, mb, M, 128);
    gather_max_kernel<<<gather_grid, 256, 0, stream>>>(
        (const u16x8*)mb, csr, offsets, counts, (u16x8*)agg, M);
    mfma_gemm_kernel<8, true, 2, false><<<gemm_grid, 256, 0, stream>>>(
        in_b, wb_s1, agg, wb_n1, b_sn1, h1, M, 128);

    // ---- Layer 2 ----
    mfma_gemm_kernel<8, true, 1, false><<<gemm_grid, 256, 0, stream>>>(
        h1, wb_p2, nullptr, nullptr, pb2, mb, M, 128);
    gather_max_kernel<<<gather_grid, 256, 0, stream>>>(
        (const u16x8*)mb, csr, offsets, counts, (u16x8*)agg, M);
    mfma_gemm_kernel<3, false, 2, true><<<gemm_grid, 256, 0, stream>>>(
        h1, wb_s2, agg, wb_n2, b_sn2, out, M, 40);
}